// Round 18
// baseline (294.563 us; speedup 1.0000x reference)
//
#include <hip/hip_runtime.h>

#define HH 512
#define WW 512
#define HWC (HH * WW)          // 262144 = 2^18
#define NV 50000
#define NB 4
#define NR (NB * NV)           // 200000 rows per branch
#define NQ (2 * NR)            // 400000 total queries
#define KVROWS (NR + 1)        // +1 dummy bias row per branch

typedef unsigned int uint32;
typedef unsigned short ushort16;

static __device__ __forceinline__ float4 ld4(const float* p) {
    return *reinterpret_cast<const float4*>(p);
}
// round-to-nearest-even f32 -> bf16 (as low 16 bits)
static __device__ __forceinline__ uint32 bf16rne(float x) {
    uint32 u = __float_as_uint(x);
    return (u + 0x7FFFu + ((u >> 16) & 1u)) >> 16;
}
static __device__ __forceinline__ uint32 pack2(float a, float b) {
    return bf16rne(a) | (bf16rne(b) << 16);
}
// DPP ctrl must be an integer-constant expression -> template.
template <int CTRL>
static __device__ __forceinline__ float dpp_add(float x) {
    float t = __int_as_float(__builtin_amdgcn_update_dpp(0, __float_as_int(x), CTRL, 0xF, 0xF, true));
    return x + t;
}

// 2-way bf16 dot-accumulate. Builtin (compiler-scheduled, unlike round-14's
// asm) when available; scalar-FMA fallback otherwise (same math, fp32 products).
typedef short sh2 __attribute__((ext_vector_type(2)));
#if defined(__has_builtin) && __has_builtin(__builtin_amdgcn_fdot2_f32_bf16)
static __device__ __forceinline__ float dot2bf(uint32 a, uint32 b, float c) {
    union U { uint32 u; sh2 v; };
    U ua; ua.u = a;
    U ub; ub.u = b;
    return __builtin_amdgcn_fdot2_f32_bf16(ua.v, ub.v, c, false);
}
#else
static __device__ __forceinline__ float dot2bf(uint32 a, uint32 b, float c) {
    return fmaf(__uint_as_float(a << 16), __uint_as_float(b << 16),
           fmaf(__uint_as_float(a & 0xFFFF0000u), __uint_as_float(b & 0xFFFF0000u), c));
}
#endif

// ---------------------------------------------------------------------------
// K0: fast -1 fill of the grids buffer.
// ---------------------------------------------------------------------------
__global__ void k_fill(int4* __restrict__ p) {
    const int total = 2 * NB * HWC / 4;
    const int stride = gridDim.x * blockDim.x;
    const int4 v = make_int4(-1, -1, -1, -1);
    for (int i = blockIdx.x * blockDim.x + threadIdx.x; i < total; i += stride)
        p[i] = v;
}

// ---------------------------------------------------------------------------
// K1: scatter voxel indices into dense coord->index grids
// grids layout: [set(0=li,1=ra)][b][HWC], pre-filled with -1
// ---------------------------------------------------------------------------
__global__ void k_grid(const int* __restrict__ li_coors, const int* __restrict__ ra_coors,
                       int* __restrict__ grids) {
    int t = blockIdx.x * blockDim.x + threadIdx.x;
    if (t >= NQ) return;
    int set = t / NR;
    int r2 = t - set * NR;
    int b = r2 / NV;
    int n = r2 - b * NV;
    const int* co = (set == 0 ? li_coors : ra_coors) + (size_t)(b * NV + n) * 2;
    grids[(set * NB + b) * HWC + co[0] * WW + co[1]] = n;
}

// ---------------------------------------------------------------------------
// K2: K|V projection, wave-loop + 2-deep pipeline (round-10 structure).
// blockIdx.y = f (feats tensor). Output: packed KV[f^1] (K low16, V high16),
// plane layout [KVROWS][32] u32 — row NR is the DUMMY BIAS ROW (bk|bv).
// ---------------------------------------------------------------------------
__launch_bounds__(256)
__global__ void k_proj_kv(const float* __restrict__ li_feats, const float* __restrict__ ra_feats,
                          const float* __restrict__ w_qkv1, const float* __restrict__ b_qkv1,
                          const float* __restrict__ w_qkv2, const float* __restrict__ b_qkv2,
                          uint32* __restrict__ KV) {
    const int f = blockIdx.y;
    const float* feats = f ? ra_feats : li_feats;
    const float* wkv_g = f ? w_qkv1 : w_qkv2;   // weights of branch f^1
    const float* bkv_g = f ? b_qkv1 : b_qkv2;

    __shared__ float xs[4][2][64];
    const int wave = threadIdx.x >> 6;
    const int l    = threadIdx.x & 63;
    const int h    = l >> 5;         // which row of the pair
    const int j    = l & 31;         // output column

    const int gw = blockIdx.x * 4 + wave;          // global wave id
    const int gs = gridDim.x * 4;                  // wave stride

    int r0 = gw * 2;
    float xreg = feats[(size_t)r0 * 32 + l];       // prefetch pair 0 first

    float4 wk[8], wv[8];
#pragma unroll
    for (int i = 0; i < 8; ++i) {
        wk[i] = ld4(wkv_g + (32 + j) * 32 + i * 4);
        wv[i] = ld4(wkv_g + (64 + j) * 32 + i * 4);
    }
    const float bk = bkv_g[32 + j], bv = bkv_g[64 + j];

    uint32* KVb = KV + (size_t)(f ^ 1) * KVROWS * 32;

    if (blockIdx.x == 0 && threadIdx.x < 32)       // dummy bias row
        KVb[(size_t)NR * 32 + threadIdx.x] = pack2(bk, bv);

    int cur = 0;
    while (r0 < NR) {
        xs[wave][cur][l] = xreg;                   // stage current pair
        const int rn = r0 + gs * 2;
        if (rn < NR) xreg = feats[(size_t)rn * 32 + l];  // issue next load NOW

        const float* xp = &xs[wave][cur][h * 32];
        float ak = bk, av = bv;
#pragma unroll
        for (int i = 0; i < 8; ++i) {
            float4 x = *reinterpret_cast<const float4*>(xp + i * 4);  // broadcast
            ak += x.x * wk[i].x + x.y * wk[i].y + x.z * wk[i].z + x.w * wk[i].w;
            av += x.x * wv[i].x + x.y * wv[i].y + x.z * wv[i].z + x.w * wv[i].w;
        }
        KVb[(size_t)(r0 + h) * 32 + j] = pack2(ak, av);
        r0 = rn;
        cur ^= 1;
    }
}

// ---------------------------------------------------------------------------
// K3a: neighbor resolve. 1 thread per query; 9 independent grid loads.
// Writes [q][12]: BYTE offsets into the branch KV plane (bb*NV folded in;
// invalid/empty -> dummy row NR), plus 3 pad ints.
// ---------------------------------------------------------------------------
__global__ void k_nbr(const int* __restrict__ li_coors, const int* __restrict__ ra_coors,
                      const int* __restrict__ grids, int* __restrict__ nbr) {
    int q = blockIdx.x * 256 + threadIdx.x;
    if (q >= NQ) return;
    int br  = (q >= NR) ? 1 : 0;
    int rem = q - br * NR;
    int b   = rem / NV;
    const int* qc = br ? ra_coors : li_coors;
    const int* kvgrid = grids + ((br ^ 1) * NB + b) * HWC;
    const int2 rc = *reinterpret_cast<const int2*>(qc + (size_t)rem * 2);

    const int drs[9] = {0, -1, 1, 0, -1, 1, 0, -1, 1};
    const int dcs[9] = {0, 0, 0, 1, 1, 1, -1, -1, -1};
    const int base = b * NV;
    int v[9];
#pragma unroll
    for (int k = 0; k < 9; ++k) {
        int rr = rc.x + drs[k], cc = rc.y + dcs[k];
        bool valid = ((unsigned)rr < HH) & ((unsigned)cc < WW);
        int raw = kvgrid[valid ? rr * WW + cc : 0];
        int id = valid ? raw : -1;
        v[k] = (id >= 0 ? base + id : NR) * 128;   // byte offset; dummy row if miss
    }
    int4* np = reinterpret_cast<int4*>(nbr + (size_t)q * 12);
    np[0] = make_int4(v[0], v[1], v[2], v[3]);
    np[1] = make_int4(v[4], v[5], v[6], v[7]);
    np[2] = make_int4(v[8], 0, 0, 0);
}

// ---------------------------------------------------------------------------
// K3b: FUSED attention core, three-stage lane remap + bf16 dot2 projections:
//   A (32 lanes/query): Q-proj as bf16 dot2 (wq packed bf16x2 in VGPRs,
//     feats rows packed bf16 in LDS) — halves FMA and LDS-read counts.
//   B (8 lanes/query, 4 channels/lane): in-lane dot4 + 2-step quad_perm DPP
//     (quads == heads), exp2, PV accumulate. Writes o packed bf16x2.
//   C (32 lanes/query): out-proj as bf16 dot2 + fp32 residual; res in bf16.
// Intermediates via padded LDS, all intra-wave (no barriers). Gathers issue
// before stage A so projection math hides their latency.
// ---------------------------------------------------------------------------
__launch_bounds__(256)
__global__ void k_attn(const int* __restrict__ nbr,
                       const float* __restrict__ li_feats, const float* __restrict__ ra_feats,
                       const float* __restrict__ w_qkv1, const float* __restrict__ b_qkv1,
                       const float* __restrict__ w_out1, const float* __restrict__ b_out1,
                       const float* __restrict__ w_qkv2, const float* __restrict__ b_qkv2,
                       const float* __restrict__ w_out2, const float* __restrict__ b_out2,
                       const uint32* __restrict__ KV, ushort16* __restrict__ resh) {
    __shared__ ushort16 xsh[8][4][32];  // feats rows, bf16 (A mapping)
    __shared__ float Qls[4][8][36];     // scaled Q fp32, padded rows
    __shared__ uint32 osu[4][8][20];    // o rows, bf16x2 packed, padded
    const int tid = threadIdx.x;
    const int w = tid >> 6;            // wave in block
    const int l = tid & 63;            // lane in wave
    const int g = tid >> 5;            // 32-lane group (A/C mapping)
    const int j = tid & 31;
    const int wq0 = (blockIdx.x * 4 + w) * 8;    // wave's first query
    const int br  = (wq0 >= NR) ? 1 : 0;
    const float* feats = br ? ra_feats : li_feats;
    const float* wqkv  = br ? w_qkv2 : w_qkv1;
    const float* bqkv  = br ? b_qkv2 : b_qkv1;
    const float* wout  = br ? w_out2 : w_out1;
    const float* bout  = br ? b_out2 : b_out1;
    const char* KVbr = (const char*)(KV + (size_t)br * KVROWS * 32);

    // ---- B mapping: nbr offsets + all 9 dwordx4 gathers issued first ---
    const int qB = wq0 + (l >> 3);                // this lane's B query
    const int4* np = reinterpret_cast<const int4*>(nbr + (size_t)qB * 12);
    int4 b0 = np[0], b1 = np[1], b2 = np[2];
    const int coff = (l & 7) * 16;                // channel-byte offset
    int off[9] = {b0.x, b0.y, b0.z, b0.w, b1.x, b1.y, b1.z, b1.w, b2.x};
    uint4 kv4[9];
#pragma unroll
    for (int k = 0; k < 9; ++k)
        kv4[k] = *reinterpret_cast<const uint4*>(KVbr + (size_t)(unsigned)(off[k] + coff));

    // ---- Stage A: feats rows (bf16 to LDS) + Q projection --------------
    const int qrow = (l >> 5) << 2;               // 0 or 4: wave-local query base
    const int remA = wq0 + qrow - br * NR;
    float fr[4];
#pragma unroll
    for (int u = 0; u < 4; ++u) {
        fr[u] = feats[(size_t)(remA + u) * 32 + j];
        xsh[g][u][j] = (ushort16)bf16rne(fr[u]);
    }
    uint32 wq16[16];
#pragma unroll
    for (int i = 0; i < 8; ++i) {
        float4 wv4 = ld4(wqkv + j * 32 + i * 4);
        wq16[2 * i]     = pack2(wv4.x, wv4.y);
        wq16[2 * i + 1] = pack2(wv4.z, wv4.w);
    }
    const float bq = bqkv[j];
    float Qf[4] = {bq, bq, bq, bq};
#pragma unroll
    for (int i = 0; i < 4; ++i) {
#pragma unroll
        for (int u = 0; u < 4; ++u) {
            uint4 x = *reinterpret_cast<const uint4*>(&xsh[g][u][i * 8]);  // broadcast
            Qf[u] = dot2bf(wq16[i * 4 + 0], x.x, Qf[u]);
            Qf[u] = dot2bf(wq16[i * 4 + 1], x.y, Qf[u]);
            Qf[u] = dot2bf(wq16[i * 4 + 2], x.z, Qf[u]);
            Qf[u] = dot2bf(wq16[i * 4 + 3], x.w, Qf[u]);
        }
    }
    const float SC = 0.25f * 1.44269504f;   // 1/sqrt(16) * log2(e)
#pragma unroll
    for (int u = 0; u < 4; ++u) Qls[w][qrow + u][j] = Qf[u] * SC;

    // ---- Stage B: scores + softmax + PV (8 lanes/query) ---------------
    float4 q4 = *reinterpret_cast<const float4*>(&Qls[w][l >> 3][(l & 7) * 4]);
    float o0 = 0.f, o1 = 0.f, o2 = 0.f, o3 = 0.f, sum = 0.f;
#pragma unroll
    for (int k = 0; k < 9; ++k) {
        uint4 c = kv4[k];
        float k0 = __uint_as_float(c.x << 16);
        float k1 = __uint_as_float(c.y << 16);
        float k2 = __uint_as_float(c.z << 16);
        float k3 = __uint_as_float(c.w << 16);
        float d = q4.x * k0 + q4.y * k1 + q4.z * k2 + q4.w * k3;
        d = dpp_add<0xB1>(d);                     // quad_perm(1,0,3,2)
        d = dpp_add<0x4E>(d);                     // quad_perm(2,3,0,1) -> quad sum
        float e = exp2f(d);                       // quads == heads: per-head score
        sum += e;
        o0 += e * __uint_as_float(c.x & 0xFFFF0000u);
        o1 += e * __uint_as_float(c.y & 0xFFFF0000u);
        o2 += e * __uint_as_float(c.z & 0xFFFF0000u);
        o3 += e * __uint_as_float(c.w & 0xFFFF0000u);
    }
    const float rs = 1.0f / sum;                  // per-head denominator
    *reinterpret_cast<uint2*>(&osu[w][l >> 3][(l & 7) * 2]) =
        make_uint2(pack2(o0 * rs, o1 * rs), pack2(o2 * rs, o3 * rs));

    // ---- Stage C: out-projection (bf16 dot2) + residual ----------------
    uint32 wo16[16];
#pragma unroll
    for (int i = 0; i < 8; ++i) {
        float4 wv4 = ld4(wout + j * 32 + i * 4);
        wo16[2 * i]     = pack2(wv4.x, wv4.y);
        wo16[2 * i + 1] = pack2(wv4.z, wv4.w);
    }
    const float bo = bout[j];
    float outv[4] = {bo, bo, bo, bo};
#pragma unroll
    for (int i = 0; i < 4; ++i) {
#pragma unroll
        for (int u = 0; u < 4; ++u) {
            uint4 x = *reinterpret_cast<const uint4*>(&osu[w][qrow + u][i * 4]);  // broadcast
            outv[u] = dot2bf(wo16[i * 4 + 0], x.x, outv[u]);
            outv[u] = dot2bf(wo16[i * 4 + 1], x.y, outv[u]);
            outv[u] = dot2bf(wo16[i * 4 + 2], x.z, outv[u]);
            outv[u] = dot2bf(wo16[i * 4 + 3], x.w, outv[u]);
        }
    }
#pragma unroll
    for (int u = 0; u < 4; ++u)
        resh[(size_t)(wq0 + qrow + u) * 32 + j] = (ushort16)bf16rne(fr[u] + outv[u]);
}

// ---------------------------------------------------------------------------
// K4: densify (inverted scatter). One thread per output cell; reads the 64B
// bf16 res row (or zeros), writes all 32 channel planes coalesced with
// NON-TEMPORAL stores (out is never re-read).
// ---------------------------------------------------------------------------
__launch_bounds__(256)
__global__ void k_densify(const int* __restrict__ grids, const ushort16* __restrict__ resh,
                          float* __restrict__ out) {
    int t = blockIdx.x * 256 + threadIdx.x;  // 0 .. 2*NB*HWC-1
    int plane = t >> 18;                     // (br*NB + b)
    int s = t & (HWC - 1);
    int gidx = grids[t];                     // query grid (set==branch)
    uint4 r[4];
    if (gidx >= 0) {
        const uint4* rp = reinterpret_cast<const uint4*>(resh + (size_t)(plane * (size_t)NV + gidx) * 32);
#pragma unroll
        for (int i = 0; i < 4; ++i) r[i] = rp[i];
    } else {
#pragma unroll
        for (int i = 0; i < 4; ++i) r[i] = make_uint4(0, 0, 0, 0);
    }
    float* ob = out + (size_t)plane * 32 * HWC + s;
#pragma unroll
    for (int i = 0; i < 4; ++i) {
        uint32 um[4] = {r[i].x, r[i].y, r[i].z, r[i].w};
#pragma unroll
        for (int m = 0; m < 4; ++m) {
            int c = i * 8 + m * 2;
            __builtin_nontemporal_store(__uint_as_float(um[m] << 16), ob + (size_t)c * HWC);
            __builtin_nontemporal_store(__uint_as_float(um[m] & 0xFFFF0000u), ob + (size_t)(c + 1) * HWC);
        }
    }
}

// ---------------------------------------------------------------------------
extern "C" void kernel_launch(void* const* d_in, const int* in_sizes, int n_in,
                              void* d_out, int out_size, void* d_ws, size_t ws_size,
                              hipStream_t stream) {
    const float* li_feats = (const float*)d_in[0];
    const int*   li_coors = (const int*)d_in[1];
    const float* ra_feats = (const float*)d_in[2];
    const int*   ra_coors = (const int*)d_in[3];
    const float* w_qkv1 = (const float*)d_in[4];
    const float* b_qkv1 = (const float*)d_in[5];
    const float* w_out1 = (const float*)d_in[6];
    const float* b_out1 = (const float*)d_in[7];
    const float* w_qkv2 = (const float*)d_in[8];
    const float* b_qkv2 = (const float*)d_in[9];
    const float* w_out2 = (const float*)d_in[10];
    const float* b_out2 = (const float*)d_in[11];
    float* out = (float*)d_out;

    char* ws = (char*)d_ws;
    size_t off = 0;
    int*      grids = (int*)(ws + off);      off += (size_t)2 * NB * HWC * 4;    // 8 MB
    uint32*   KV    = (uint32*)(ws + off);   off += (size_t)2 * KVROWS * 32 * 4; // 51.2 MB
    ushort16* resh  = (ushort16*)(ws + off); off += (size_t)NQ * 32 * 2;         // 25.6 MB bf16
    int*      nbr   = (int*)(ws + off);      off += (size_t)NQ * 12 * 4;         // 19.2 MB

    k_fill<<<2048, 256, 0, stream>>>((int4*)grids);

    k_grid<<<(NQ + 255) / 256, 256, 0, stream>>>(li_coors, ra_coors, grids);

    k_proj_kv<<<dim3(6400, 2), 256, 0, stream>>>(
        li_feats, ra_feats, w_qkv1, b_qkv1, w_qkv2, b_qkv2, KV);

    k_nbr<<<(NQ + 255) / 256, 256, 0, stream>>>(li_coors, ra_coors, grids, nbr);

    k_attn<<<NQ / 32, 256, 0, stream>>>(
        nbr, li_feats, ra_feats,
        w_qkv1, b_qkv1, w_out1, b_out1,
        w_qkv2, b_qkv2, w_out2, b_out2,
        KV, resh);

    k_densify<<<(2 * NB * HWC) / 256, 256, 0, stream>>>(grids, resh, out);
}

// Round 19
// 256.229 us; speedup vs baseline: 1.1496x; 1.1496x over previous
//
#include <hip/hip_runtime.h>

#define HH 512
#define WW 512
#define HWC (HH * WW)          // 262144 = 2^18
#define NV 50000
#define NB 4
#define NR (NB * NV)           // 200000 rows per branch
#define NQ (2 * NR)            // 400000 total queries
#define KVROWS (NR + 1)        // +1 dummy bias row per branch

typedef unsigned int uint32;
typedef unsigned short ushort16;

static __device__ __forceinline__ float4 ld4(const float* p) {
    return *reinterpret_cast<const float4*>(p);
}
// round-to-nearest-even f32 -> bf16 (as low 16 bits)
static __device__ __forceinline__ uint32 bf16rne(float x) {
    uint32 u = __float_as_uint(x);
    return (u + 0x7FFFu + ((u >> 16) & 1u)) >> 16;
}
// DPP ctrl must be an integer-constant expression -> template.
template <int CTRL>
static __device__ __forceinline__ float dpp_add(float x) {
    float t = __int_as_float(__builtin_amdgcn_update_dpp(0, __float_as_int(x), CTRL, 0xF, 0xF, true));
    return x + t;
}

// ---------------------------------------------------------------------------
// K0: fast -1 fill of the grids buffer.
// ---------------------------------------------------------------------------
__global__ void k_fill(int4* __restrict__ p) {
    const int total = 2 * NB * HWC / 4;
    const int stride = gridDim.x * blockDim.x;
    const int4 v = make_int4(-1, -1, -1, -1);
    for (int i = blockIdx.x * blockDim.x + threadIdx.x; i < total; i += stride)
        p[i] = v;
}

// ---------------------------------------------------------------------------
// K1: scatter voxel indices into dense coord->index grids
// grids layout: [set(0=li,1=ra)][b][HWC], pre-filled with -1
// ---------------------------------------------------------------------------
__global__ void k_grid(const int* __restrict__ li_coors, const int* __restrict__ ra_coors,
                       int* __restrict__ grids) {
    int t = blockIdx.x * blockDim.x + threadIdx.x;
    if (t >= NQ) return;
    int set = t / NR;
    int r2 = t - set * NR;
    int b = r2 / NV;
    int n = r2 - b * NV;
    const int* co = (set == 0 ? li_coors : ra_coors) + (size_t)(b * NV + n) * 2;
    grids[(set * NB + b) * HWC + co[0] * WW + co[1]] = n;
}

// ---------------------------------------------------------------------------
// K2: K|V projection, wave-loop + 2-deep pipeline (round-10 structure).
// blockIdx.y = f (feats tensor). Output: packed KV[f^1] (K low16, V high16),
// plane layout [KVROWS][32] u32 — row NR is the DUMMY BIAS ROW (bk|bv).
// ---------------------------------------------------------------------------
__launch_bounds__(256)
__global__ void k_proj_kv(const float* __restrict__ li_feats, const float* __restrict__ ra_feats,
                          const float* __restrict__ w_qkv1, const float* __restrict__ b_qkv1,
                          const float* __restrict__ w_qkv2, const float* __restrict__ b_qkv2,
                          uint32* __restrict__ KV) {
    const int f = blockIdx.y;
    const float* feats = f ? ra_feats : li_feats;
    const float* wkv_g = f ? w_qkv1 : w_qkv2;   // weights of branch f^1
    const float* bkv_g = f ? b_qkv1 : b_qkv2;

    __shared__ float xs[4][2][64];
    const int wave = threadIdx.x >> 6;
    const int l    = threadIdx.x & 63;
    const int h    = l >> 5;         // which row of the pair
    const int j    = l & 31;         // output column

    const int gw = blockIdx.x * 4 + wave;          // global wave id
    const int gs = gridDim.x * 4;                  // wave stride

    int r0 = gw * 2;
    float xreg = feats[(size_t)r0 * 32 + l];       // prefetch pair 0 first

    float4 wk[8], wv[8];
#pragma unroll
    for (int i = 0; i < 8; ++i) {
        wk[i] = ld4(wkv_g + (32 + j) * 32 + i * 4);
        wv[i] = ld4(wkv_g + (64 + j) * 32 + i * 4);
    }
    const float bk = bkv_g[32 + j], bv = bkv_g[64 + j];

    uint32* KVb = KV + (size_t)(f ^ 1) * KVROWS * 32;

    if (blockIdx.x == 0 && threadIdx.x < 32)       // dummy bias row
        KVb[(size_t)NR * 32 + threadIdx.x] = bf16rne(bk) | (bf16rne(bv) << 16);

    int cur = 0;
    while (r0 < NR) {
        xs[wave][cur][l] = xreg;                   // stage current pair
        const int rn = r0 + gs * 2;
        if (rn < NR) xreg = feats[(size_t)rn * 32 + l];  // issue next load NOW

        const float* xp = &xs[wave][cur][h * 32];
        float ak = bk, av = bv;
#pragma unroll
        for (int i = 0; i < 8; ++i) {
            float4 x = *reinterpret_cast<const float4*>(xp + i * 4);  // broadcast
            ak += x.x * wk[i].x + x.y * wk[i].y + x.z * wk[i].z + x.w * wk[i].w;
            av += x.x * wv[i].x + x.y * wv[i].y + x.z * wv[i].z + x.w * wv[i].w;
        }
        KVb[(size_t)(r0 + h) * 32 + j] = bf16rne(ak) | (bf16rne(av) << 16);
        r0 = rn;
        cur ^= 1;
    }
}

// ---------------------------------------------------------------------------
// K3a: neighbor resolve. 1 thread per query; 9 independent grid loads.
// Writes [q][12]: BYTE offsets into the branch KV plane (bb*NV folded in;
// invalid/empty -> dummy row NR), plus 3 pad ints.
// ---------------------------------------------------------------------------
__global__ void k_nbr(const int* __restrict__ li_coors, const int* __restrict__ ra_coors,
                      const int* __restrict__ grids, int* __restrict__ nbr) {
    int q = blockIdx.x * 256 + threadIdx.x;
    if (q >= NQ) return;
    int br  = (q >= NR) ? 1 : 0;
    int rem = q - br * NR;
    int b   = rem / NV;
    const int* qc = br ? ra_coors : li_coors;
    const int* kvgrid = grids + ((br ^ 1) * NB + b) * HWC;
    const int2 rc = *reinterpret_cast<const int2*>(qc + (size_t)rem * 2);

    const int drs[9] = {0, -1, 1, 0, -1, 1, 0, -1, 1};
    const int dcs[9] = {0, 0, 0, 1, 1, 1, -1, -1, -1};
    const int base = b * NV;
    int v[9];
#pragma unroll
    for (int k = 0; k < 9; ++k) {
        int rr = rc.x + drs[k], cc = rc.y + dcs[k];
        bool valid = ((unsigned)rr < HH) & ((unsigned)cc < WW);
        int raw = kvgrid[valid ? rr * WW + cc : 0];
        int id = valid ? raw : -1;
        v[k] = (id >= 0 ? base + id : NR) * 128;   // byte offset; dummy row if miss
    }
    int4* np = reinterpret_cast<int4*>(nbr + (size_t)q * 12);
    np[0] = make_int4(v[0], v[1], v[2], v[3]);
    np[1] = make_int4(v[4], v[5], v[6], v[7]);
    np[2] = make_int4(v[8], 0, 0, 0);
}

// ---------------------------------------------------------------------------
// K3b: FUSED attention core, three-stage lane remap (round-17 known-best
// structure; round-18's bf16-dot2 projections regressed — packing overhead
// cancels the halved FMA count; scalar fp32 FMA with 4 chains is the local
// optimum for E=32 matvecs):
//   A (32 lanes/query): Q-proj with wq rows in VGPRs.
//   B (8 lanes/query, 4 channels/lane): in-lane dot4 + 2-step quad_perm DPP
//     (quads == heads), exp2, PV accumulate.
//   C (32 lanes/query): out-proj + residual; res stored BF16 (round 19:
//     halves attn write + densify gather traffic; values ~<=4 so rounding
//     error <= 0.016).
// ---------------------------------------------------------------------------
__launch_bounds__(256)
__global__ void k_attn(const int* __restrict__ nbr,
                       const float* __restrict__ li_feats, const float* __restrict__ ra_feats,
                       const float* __restrict__ w_qkv1, const float* __restrict__ b_qkv1,
                       const float* __restrict__ w_out1, const float* __restrict__ b_out1,
                       const float* __restrict__ w_qkv2, const float* __restrict__ b_qkv2,
                       const float* __restrict__ w_out2, const float* __restrict__ b_out2,
                       const uint32* __restrict__ KV, ushort16* __restrict__ resh) {
    __shared__ float xs[8][4][32];     // feats rows (A mapping)
    __shared__ float Qls[4][8][36];    // scaled Q, padded rows
    __shared__ float os[4][8][36];     // attention outputs, padded rows
    const int tid = threadIdx.x;
    const int w = tid >> 6;            // wave in block
    const int l = tid & 63;            // lane in wave
    const int g = tid >> 5;            // 32-lane group (A/C mapping)
    const int j = tid & 31;
    const int wq0 = (blockIdx.x * 4 + w) * 8;    // wave's first query
    const int br  = (wq0 >= NR) ? 1 : 0;
    const float* feats = br ? ra_feats : li_feats;
    const float* wqkv  = br ? w_qkv2 : w_qkv1;
    const float* bqkv  = br ? b_qkv2 : b_qkv1;
    const float* wout  = br ? w_out2 : w_out1;
    const float* bout  = br ? b_out2 : b_out1;
    const char* KVbr = (const char*)(KV + (size_t)br * KVROWS * 32);

    // ---- B mapping: nbr offsets + all 9 dwordx4 gathers issued first ---
    const int qB = wq0 + (l >> 3);                // this lane's B query
    const int4* np = reinterpret_cast<const int4*>(nbr + (size_t)qB * 12);
    int4 b0 = np[0], b1 = np[1], b2 = np[2];
    const int coff = (l & 7) * 16;                // channel-byte offset
    int off[9] = {b0.x, b0.y, b0.z, b0.w, b1.x, b1.y, b1.z, b1.w, b2.x};
    uint4 kv4[9];
#pragma unroll
    for (int k = 0; k < 9; ++k)
        kv4[k] = *reinterpret_cast<const uint4*>(KVbr + (size_t)(unsigned)(off[k] + coff));

    // ---- Stage A: feats rows + Q projection (32 lanes/query) ----------
    const int qrow = (l >> 5) << 2;               // 0 or 4: wave-local query base
    const int remA = wq0 + qrow - br * NR;
    float fr[4];
#pragma unroll
    for (int u = 0; u < 4; ++u) {
        fr[u] = feats[(size_t)(remA + u) * 32 + j];
        xs[g][u][j] = fr[u];
    }
    const float bq = bqkv[j];
    float Qf[4] = {bq, bq, bq, bq};
#pragma unroll
    for (int i = 0; i < 8; ++i) {
        float4 wv4 = ld4(wqkv + j * 32 + i * 4);
#pragma unroll
        for (int u = 0; u < 4; ++u) {
            float4 x = *reinterpret_cast<const float4*>(&xs[g][u][i * 4]);
            Qf[u] += x.x * wv4.x + x.y * wv4.y + x.z * wv4.z + x.w * wv4.w;
        }
    }
    const float SC = 0.25f * 1.44269504f;   // 1/sqrt(16) * log2(e)
#pragma unroll
    for (int u = 0; u < 4; ++u) Qls[w][qrow + u][j] = Qf[u] * SC;

    // ---- Stage B: scores + softmax + PV (8 lanes/query) ---------------
    float4 q4 = *reinterpret_cast<const float4*>(&Qls[w][l >> 3][(l & 7) * 4]);
    float o0 = 0.f, o1 = 0.f, o2 = 0.f, o3 = 0.f, sum = 0.f;
#pragma unroll
    for (int k = 0; k < 9; ++k) {
        uint4 c = kv4[k];
        float k0 = __uint_as_float(c.x << 16);
        float k1 = __uint_as_float(c.y << 16);
        float k2 = __uint_as_float(c.z << 16);
        float k3 = __uint_as_float(c.w << 16);
        float d = q4.x * k0 + q4.y * k1 + q4.z * k2 + q4.w * k3;
        d = dpp_add<0xB1>(d);                     // quad_perm(1,0,3,2)
        d = dpp_add<0x4E>(d);                     // quad_perm(2,3,0,1) -> quad sum
        float e = exp2f(d);                       // quads == heads: per-head score
        sum += e;
        o0 += e * __uint_as_float(c.x & 0xFFFF0000u);
        o1 += e * __uint_as_float(c.y & 0xFFFF0000u);
        o2 += e * __uint_as_float(c.z & 0xFFFF0000u);
        o3 += e * __uint_as_float(c.w & 0xFFFF0000u);
    }
    const float rs = 1.0f / sum;                  // per-head denominator
    *reinterpret_cast<float4*>(&os[w][l >> 3][(l & 7) * 4]) =
        make_float4(o0 * rs, o1 * rs, o2 * rs, o3 * rs);

    // ---- Stage C: out-projection + residual (32 lanes/query) ----------
    const float bo = bout[j];
    float outv[4] = {bo, bo, bo, bo};
#pragma unroll
    for (int i = 0; i < 8; ++i) {
        float4 wv4 = ld4(wout + j * 32 + i * 4);
#pragma unroll
        for (int u = 0; u < 4; ++u) {
            float4 x = *reinterpret_cast<const float4*>(&os[w][qrow + u][i * 4]);  // broadcast
            outv[u] += x.x * wv4.x + x.y * wv4.y + x.z * wv4.z + x.w * wv4.w;
        }
    }
#pragma unroll
    for (int u = 0; u < 4; ++u)
        resh[(size_t)(wq0 + qrow + u) * 32 + j] = (ushort16)bf16rne(fr[u] + outv[u]);
}

// ---------------------------------------------------------------------------
// K4: densify (inverted scatter). One thread per output cell; reads the 64B
// bf16 res row (or zeros), writes all 32 channel planes coalesced with
// NON-TEMPORAL stores (out is never re-read).
// ---------------------------------------------------------------------------
__launch_bounds__(256)
__global__ void k_densify(const int* __restrict__ grids, const ushort16* __restrict__ resh,
                          float* __restrict__ out) {
    int t = blockIdx.x * 256 + threadIdx.x;  // 0 .. 2*NB*HWC-1
    int plane = t >> 18;                     // (br*NB + b)
    int s = t & (HWC - 1);
    int gidx = grids[t];                     // query grid (set==branch)
    uint4 r[4];
    if (gidx >= 0) {
        const uint4* rp = reinterpret_cast<const uint4*>(resh + ((size_t)plane * NV + gidx) * 32);
#pragma unroll
        for (int i = 0; i < 4; ++i) r[i] = rp[i];
    } else {
#pragma unroll
        for (int i = 0; i < 4; ++i) r[i] = make_uint4(0, 0, 0, 0);
    }
    float* ob = out + (size_t)plane * 32 * HWC + s;
#pragma unroll
    for (int i = 0; i < 4; ++i) {
        uint32 um[4] = {r[i].x, r[i].y, r[i].z, r[i].w};
#pragma unroll
        for (int m = 0; m < 4; ++m) {
            int c = i * 8 + m * 2;
            __builtin_nontemporal_store(__uint_as_float(um[m] << 16), ob + (size_t)c * HWC);
            __builtin_nontemporal_store(__uint_as_float(um[m] & 0xFFFF0000u), ob + (size_t)(c + 1) * HWC);
        }
    }
}

// ---------------------------------------------------------------------------
extern "C" void kernel_launch(void* const* d_in, const int* in_sizes, int n_in,
                              void* d_out, int out_size, void* d_ws, size_t ws_size,
                              hipStream_t stream) {
    const float* li_feats = (const float*)d_in[0];
    const int*   li_coors = (const int*)d_in[1];
    const float* ra_feats = (const float*)d_in[2];
    const int*   ra_coors = (const int*)d_in[3];
    const float* w_qkv1 = (const float*)d_in[4];
    const float* b_qkv1 = (const float*)d_in[5];
    const float* w_out1 = (const float*)d_in[6];
    const float* b_out1 = (const float*)d_in[7];
    const float* w_qkv2 = (const float*)d_in[8];
    const float* b_qkv2 = (const float*)d_in[9];
    const float* w_out2 = (const float*)d_in[10];
    const float* b_out2 = (const float*)d_in[11];
    float* out = (float*)d_out;

    char* ws = (char*)d_ws;
    size_t off = 0;
    int*      grids = (int*)(ws + off);      off += (size_t)2 * NB * HWC * 4;    // 8 MB
    uint32*   KV    = (uint32*)(ws + off);   off += (size_t)2 * KVROWS * 32 * 4; // 51.2 MB
    ushort16* resh  = (ushort16*)(ws + off); off += (size_t)NQ * 32 * 2;         // 25.6 MB bf16
    int*      nbr   = (int*)(ws + off);      off += (size_t)NQ * 12 * 4;         // 19.2 MB

    k_fill<<<2048, 256, 0, stream>>>((int4*)grids);

    k_grid<<<(NQ + 255) / 256, 256, 0, stream>>>(li_coors, ra_coors, grids);

    k_proj_kv<<<dim3(3200, 2), 256, 0, stream>>>(
        li_feats, ra_feats, w_qkv1, b_qkv1, w_qkv2, b_qkv2, KV);

    k_nbr<<<(NQ + 255) / 256, 256, 0, stream>>>(li_coors, ra_coors, grids, nbr);

    k_attn<<<NQ / 32, 256, 0, stream>>>(
        nbr, li_feats, ra_feats,
        w_qkv1, b_qkv1, w_out1, b_out1,
        w_qkv2, b_qkv2, w_out2, b_out2,
        KV, resh);

    k_densify<<<(2 * NB * HWC) / 256, 256, 0, stream>>>(grids, resh, out);
}

// Round 20
// 248.892 us; speedup vs baseline: 1.1835x; 1.0295x over previous
//
#include <hip/hip_runtime.h>

#define HH 512
#define WW 512
#define HWC (HH * WW)          // 262144 = 2^18
#define NV 50000
#define NB 4
#define NR (NB * NV)           // 200000 rows per branch
#define NQ (2 * NR)            // 400000 total queries
#define KVROWS (NR + 1)        // +1 dummy bias row per branch

typedef unsigned int uint32;
typedef unsigned short ushort16;

static __device__ __forceinline__ float4 ld4(const float* p) {
    return *reinterpret_cast<const float4*>(p);
}
// round-to-nearest-even f32 -> bf16 (as low 16 bits)
static __device__ __forceinline__ uint32 bf16rne(float x) {
    uint32 u = __float_as_uint(x);
    return (u + 0x7FFFu + ((u >> 16) & 1u)) >> 16;
}
// DPP ctrl must be an integer-constant expression -> template.
template <int CTRL>
static __device__ __forceinline__ float dpp_add(float x) {
    float t = __int_as_float(__builtin_amdgcn_update_dpp(0, __float_as_int(x), CTRL, 0xF, 0xF, true));
    return x + t;
}

// ---------------------------------------------------------------------------
// K0: fast -1 fill of the grids buffer.
// ---------------------------------------------------------------------------
__global__ void k_fill(int4* __restrict__ p) {
    const int total = 2 * NB * HWC / 4;
    const int stride = gridDim.x * blockDim.x;
    const int4 v = make_int4(-1, -1, -1, -1);
    for (int i = blockIdx.x * blockDim.x + threadIdx.x; i < total; i += stride)
        p[i] = v;
}

// ---------------------------------------------------------------------------
// K1: scatter voxel indices into dense coord->index grids
// grids layout: [set(0=li,1=ra)][b][HWC], pre-filled with -1
// ---------------------------------------------------------------------------
__global__ void k_grid(const int* __restrict__ li_coors, const int* __restrict__ ra_coors,
                       int* __restrict__ grids) {
    int t = blockIdx.x * blockDim.x + threadIdx.x;
    if (t >= NQ) return;
    int set = t / NR;
    int r2 = t - set * NR;
    int b = r2 / NV;
    int n = r2 - b * NV;
    const int* co = (set == 0 ? li_coors : ra_coors) + (size_t)(b * NV + n) * 2;
    grids[(set * NB + b) * HWC + co[0] * WW + co[1]] = n;
}

// ---------------------------------------------------------------------------
// K2: combined projection (round-20: Q-proj moved back here from attn — this
// kernel's wave-loop is latency-bound, so the extra accumulator rides free).
// blockIdx.y = f (feats tensor). Per row:
//   K,V (weights of branch f^1) -> packed KV[f^1], row NR = dummy bias row.
//   Q   (weights of branch f)   -> Qbuf[f] bf16.
// Wave-loop + 2-deep pipeline (round-10 structure).
// ---------------------------------------------------------------------------
__launch_bounds__(256)
__global__ void k_proj(const float* __restrict__ li_feats, const float* __restrict__ ra_feats,
                       const float* __restrict__ w_qkv1, const float* __restrict__ b_qkv1,
                       const float* __restrict__ w_qkv2, const float* __restrict__ b_qkv2,
                       uint32* __restrict__ KV, ushort16* __restrict__ Qbuf) {
    const int f = blockIdx.y;
    const float* feats = f ? ra_feats : li_feats;
    const float* wkv_g = f ? w_qkv1 : w_qkv2;   // K/V weights of branch f^1
    const float* bkv_g = f ? b_qkv1 : b_qkv2;
    const float* wq_g  = f ? w_qkv2 : w_qkv1;   // Q weights of branch f
    const float* bq_g  = f ? b_qkv2 : b_qkv1;

    __shared__ float xs[4][2][64];
    const int wave = threadIdx.x >> 6;
    const int l    = threadIdx.x & 63;
    const int h    = l >> 5;         // which row of the pair
    const int j    = l & 31;         // output column

    const int gw = blockIdx.x * 4 + wave;          // global wave id
    const int gs = gridDim.x * 4;                  // wave stride

    int r0 = gw * 2;
    float xreg = feats[(size_t)r0 * 32 + l];       // prefetch pair 0 first

    float4 wk[8], wv[8], wq[8];
#pragma unroll
    for (int i = 0; i < 8; ++i) {
        wk[i] = ld4(wkv_g + (32 + j) * 32 + i * 4);
        wv[i] = ld4(wkv_g + (64 + j) * 32 + i * 4);
        wq[i] = ld4(wq_g + j * 32 + i * 4);
    }
    const float bk = bkv_g[32 + j], bv = bkv_g[64 + j], bq = bq_g[j];

    uint32* KVb = KV + (size_t)(f ^ 1) * KVROWS * 32;
    ushort16* Qb = Qbuf + (size_t)f * NR * 32;

    if (blockIdx.x == 0 && threadIdx.x < 32)       // dummy bias row
        KVb[(size_t)NR * 32 + threadIdx.x] = bf16rne(bk) | (bf16rne(bv) << 16);

    int cur = 0;
    while (r0 < NR) {
        xs[wave][cur][l] = xreg;                   // stage current pair
        const int rn = r0 + gs * 2;
        if (rn < NR) xreg = feats[(size_t)rn * 32 + l];  // issue next load NOW

        const float* xp = &xs[wave][cur][h * 32];
        float ak = bk, av = bv, aq = bq;
#pragma unroll
        for (int i = 0; i < 8; ++i) {
            float4 x = *reinterpret_cast<const float4*>(xp + i * 4);  // broadcast
            ak += x.x * wk[i].x + x.y * wk[i].y + x.z * wk[i].z + x.w * wk[i].w;
            av += x.x * wv[i].x + x.y * wv[i].y + x.z * wv[i].z + x.w * wv[i].w;
            aq += x.x * wq[i].x + x.y * wq[i].y + x.z * wq[i].z + x.w * wq[i].w;
        }
        KVb[(size_t)(r0 + h) * 32 + j] = bf16rne(ak) | (bf16rne(av) << 16);
        Qb[(size_t)(r0 + h) * 32 + j] = (ushort16)bf16rne(aq);
        r0 = rn;
        cur ^= 1;
    }
}

// ---------------------------------------------------------------------------
// K3a: neighbor resolve. 1 thread per query; 9 independent grid loads.
// Writes [q][12]: BYTE offsets into the branch KV plane (bb*NV folded in;
// invalid/empty -> dummy row NR), plus 3 pad ints.
// ---------------------------------------------------------------------------
__global__ void k_nbr(const int* __restrict__ li_coors, const int* __restrict__ ra_coors,
                      const int* __restrict__ grids, int* __restrict__ nbr) {
    int q = blockIdx.x * 256 + threadIdx.x;
    if (q >= NQ) return;
    int br  = (q >= NR) ? 1 : 0;
    int rem = q - br * NR;
    int b   = rem / NV;
    const int* qc = br ? ra_coors : li_coors;
    const int* kvgrid = grids + ((br ^ 1) * NB + b) * HWC;
    const int2 rc = *reinterpret_cast<const int2*>(qc + (size_t)rem * 2);

    const int drs[9] = {0, -1, 1, 0, -1, 1, 0, -1, 1};
    const int dcs[9] = {0, 0, 0, 1, 1, 1, -1, -1, -1};
    const int base = b * NV;
    int v[9];
#pragma unroll
    for (int k = 0; k < 9; ++k) {
        int rr = rc.x + drs[k], cc = rc.y + dcs[k];
        bool valid = ((unsigned)rr < HH) & ((unsigned)cc < WW);
        int raw = kvgrid[valid ? rr * WW + cc : 0];
        int id = valid ? raw : -1;
        v[k] = (id >= 0 ? base + id : NR) * 128;   // byte offset; dummy row if miss
    }
    int4* np = reinterpret_cast<int4*>(nbr + (size_t)q * 12);
    np[0] = make_int4(v[0], v[1], v[2], v[3]);
    np[1] = make_int4(v[4], v[5], v[6], v[7]);
    np[2] = make_int4(v[8], 0, 0, 0);
}

// ---------------------------------------------------------------------------
// K3b: FUSED attention core (round-20: Q-proj removed — read from Qbuf):
//   B (8 lanes/query, 4 channels/lane): Q-slice as one uint2 (4 bf16) from
//     Qbuf; in-lane dot4 + 2-step quad_perm DPP (quads == heads); softmax
//     scale folded into one post-reduce mul; PV accumulate -> os LDS.
//   C (32 lanes/query): out-proj + residual (feats read once); res bf16.
// LDS down to os only (4.6 KB). Gathers issue first; fr/Q loads + stage B
// front fill the latency window.
// ---------------------------------------------------------------------------
__launch_bounds__(256)
__global__ void k_attn(const int* __restrict__ nbr,
                       const float* __restrict__ li_feats, const float* __restrict__ ra_feats,
                       const ushort16* __restrict__ Qbuf,
                       const float* __restrict__ w_out1, const float* __restrict__ b_out1,
                       const float* __restrict__ w_out2, const float* __restrict__ b_out2,
                       const uint32* __restrict__ KV, ushort16* __restrict__ resh) {
    __shared__ float os[4][8][36];     // attention outputs, padded rows
    const int tid = threadIdx.x;
    const int w = tid >> 6;            // wave in block
    const int l = tid & 63;            // lane in wave
    const int j = tid & 31;
    const int wq0 = (blockIdx.x * 4 + w) * 8;    // wave's first query
    const int br  = (wq0 >= NR) ? 1 : 0;
    const float* feats = br ? ra_feats : li_feats;
    const float* wout  = br ? w_out2 : w_out1;
    const float* bout  = br ? b_out2 : b_out1;
    const char* KVbr = (const char*)(KV + (size_t)br * KVROWS * 32);

    // ---- B mapping: nbr offsets + all 9 dwordx4 gathers issued first ---
    const int qB = wq0 + (l >> 3);                // this lane's B query
    const int4* np = reinterpret_cast<const int4*>(nbr + (size_t)qB * 12);
    int4 b0 = np[0], b1 = np[1], b2 = np[2];
    const int coff = (l & 7) * 16;                // channel-byte offset
    int off[9] = {b0.x, b0.y, b0.z, b0.w, b1.x, b1.y, b1.z, b1.w, b2.x};
    uint4 kv4[9];
#pragma unroll
    for (int k = 0; k < 9; ++k)
        kv4[k] = *reinterpret_cast<const uint4*>(KVbr + (size_t)(unsigned)(off[k] + coff));

    // ---- Q-slice: 4 bf16 channels for this lane's query ----------------
    const uint2 qr = *reinterpret_cast<const uint2*>(
        reinterpret_cast<const ushort16*>(Qbuf) + (size_t)qB * 32 + (l & 7) * 4);
    float4 q4;
    q4.x = __uint_as_float(qr.x << 16);
    q4.y = __uint_as_float(qr.x & 0xFFFF0000u);
    q4.z = __uint_as_float(qr.y << 16);
    q4.w = __uint_as_float(qr.y & 0xFFFF0000u);

    // ---- residual rows (32 lanes/query mapping, used in stage C) -------
    const int qrow = (l >> 5) << 2;               // 0 or 4: wave-local query base
    const int remA = wq0 + qrow - br * NR;
    float fr[4];
#pragma unroll
    for (int u = 0; u < 4; ++u)
        fr[u] = feats[(size_t)(remA + u) * 32 + j];

    // ---- Stage B: scores + softmax + PV (8 lanes/query) ---------------
    const float SC = 0.25f * 1.44269504f;   // 1/sqrt(16) * log2(e)
    float o0 = 0.f, o1 = 0.f, o2 = 0.f, o3 = 0.f, sum = 0.f;
#pragma unroll
    for (int k = 0; k < 9; ++k) {
        uint4 c = kv4[k];
        float k0 = __uint_as_float(c.x << 16);
        float k1 = __uint_as_float(c.y << 16);
        float k2 = __uint_as_float(c.z << 16);
        float k3 = __uint_as_float(c.w << 16);
        float d = q4.x * k0 + q4.y * k1 + q4.z * k2 + q4.w * k3;
        d = dpp_add<0xB1>(d);                     // quad_perm(1,0,3,2)
        d = dpp_add<0x4E>(d);                     // quad_perm(2,3,0,1) -> quad sum
        float e = exp2f(d * SC);                  // quads == heads: per-head score
        sum += e;
        o0 += e * __uint_as_float(c.x & 0xFFFF0000u);
        o1 += e * __uint_as_float(c.y & 0xFFFF0000u);
        o2 += e * __uint_as_float(c.z & 0xFFFF0000u);
        o3 += e * __uint_as_float(c.w & 0xFFFF0000u);
    }
    const float rs = 1.0f / sum;                  // per-head denominator
    *reinterpret_cast<float4*>(&os[w][l >> 3][(l & 7) * 4]) =
        make_float4(o0 * rs, o1 * rs, o2 * rs, o3 * rs);

    // ---- Stage C: out-projection + residual (32 lanes/query) ----------
    const float bo = bout[j];
    float outv[4] = {bo, bo, bo, bo};
#pragma unroll
    for (int i = 0; i < 8; ++i) {
        float4 wv4 = ld4(wout + j * 32 + i * 4);
#pragma unroll
        for (int u = 0; u < 4; ++u) {
            float4 x = *reinterpret_cast<const float4*>(&os[w][qrow + u][i * 4]);  // broadcast
            outv[u] += x.x * wv4.x + x.y * wv4.y + x.z * wv4.z + x.w * wv4.w;
        }
    }
#pragma unroll
    for (int u = 0; u < 4; ++u)
        resh[(size_t)(wq0 + qrow + u) * 32 + j] = (ushort16)bf16rne(fr[u] + outv[u]);
}

// ---------------------------------------------------------------------------
// K4: densify (inverted scatter). One thread per output cell; reads the 64B
// bf16 res row (or zeros), writes all 32 channel planes coalesced with
// NON-TEMPORAL stores (out is never re-read).
// ---------------------------------------------------------------------------
__launch_bounds__(256)
__global__ void k_densify(const int* __restrict__ grids, const ushort16* __restrict__ resh,
                          float* __restrict__ out) {
    int t = blockIdx.x * 256 + threadIdx.x;  // 0 .. 2*NB*HWC-1
    int plane = t >> 18;                     // (br*NB + b)
    int s = t & (HWC - 1);
    int gidx = grids[t];                     // query grid (set==branch)
    uint4 r[4];
    if (gidx >= 0) {
        const uint4* rp = reinterpret_cast<const uint4*>(resh + ((size_t)plane * NV + gidx) * 32);
#pragma unroll
        for (int i = 0; i < 4; ++i) r[i] = rp[i];
    } else {
#pragma unroll
        for (int i = 0; i < 4; ++i) r[i] = make_uint4(0, 0, 0, 0);
    }
    float* ob = out + (size_t)plane * 32 * HWC + s;
#pragma unroll
    for (int i = 0; i < 4; ++i) {
        uint32 um[4] = {r[i].x, r[i].y, r[i].z, r[i].w};
#pragma unroll
        for (int m = 0; m < 4; ++m) {
            int c = i * 8 + m * 2;
            __builtin_nontemporal_store(__uint_as_float(um[m] << 16), ob + (size_t)c * HWC);
            __builtin_nontemporal_store(__uint_as_float(um[m] & 0xFFFF0000u), ob + (size_t)(c + 1) * HWC);
        }
    }
}

// ---------------------------------------------------------------------------
extern "C" void kernel_launch(void* const* d_in, const int* in_sizes, int n_in,
                              void* d_out, int out_size, void* d_ws, size_t ws_size,
                              hipStream_t stream) {
    const float* li_feats = (const float*)d_in[0];
    const int*   li_coors = (const int*)d_in[1];
    const float* ra_feats = (const float*)d_in[2];
    const int*   ra_coors = (const int*)d_in[3];
    const float* w_qkv1 = (const float*)d_in[4];
    const float* b_qkv1 = (const float*)d_in[5];
    const float* w_out1 = (const float*)d_in[6];
    const float* b_out1 = (const float*)d_in[7];
    const float* w_qkv2 = (const float*)d_in[8];
    const float* b_qkv2 = (const float*)d_in[9];
    const float* w_out2 = (const float*)d_in[10];
    const float* b_out2 = (const float*)d_in[11];
    float* out = (float*)d_out;

    char* ws = (char*)d_ws;
    size_t off = 0;
    int*      grids = (int*)(ws + off);      off += (size_t)2 * NB * HWC * 4;    // 8 MB
    uint32*   KV    = (uint32*)(ws + off);   off += (size_t)2 * KVROWS * 32 * 4; // 51.2 MB
    ushort16* resh  = (ushort16*)(ws + off); off += (size_t)NQ * 32 * 2;         // 25.6 MB bf16
    ushort16* Qbuf  = (ushort16*)(ws + off); off += (size_t)NQ * 32 * 2;         // 25.6 MB bf16
    int*      nbr   = (int*)(ws + off);      off += (size_t)NQ * 12 * 4;         // 19.2 MB

    k_fill<<<2048, 256, 0, stream>>>((int4*)grids);

    k_grid<<<(NQ + 255) / 256, 256, 0, stream>>>(li_coors, ra_coors, grids);

    k_proj<<<dim3(3200, 2), 256, 0, stream>>>(
        li_feats, ra_feats, w_qkv1, b_qkv1, w_qkv2, b_qkv2, KV, Qbuf);

    k_nbr<<<(NQ + 255) / 256, 256, 0, stream>>>(li_coors, ra_coors, grids, nbr);

    k_attn<<<NQ / 32, 256, 0, stream>>>(
        nbr, li_feats, ra_feats, Qbuf,
        w_out1, b_out1, w_out2, b_out2,
        KV, resh);

    k_densify<<<(2 * NB * HWC) / 256, 256, 0, stream>>>(grids, resh, out);
}